// Round 8
// baseline (12877.936 us; speedup 1.0000x reference)
//
#include <hip/hip_runtime.h>
#include <stdint.h>

// Seq2seq LSTM, f32 in/out, bf16 MFMA, fp32 cell state.
// R8:
//  Encoder (unchanged transport, R7-proven): 16 batch-groups(16 rows) x 16
//   hid-slices; weights in registers; 1 barrier/superstep; agent atomic stores
//   for h; NEW: peer h slabs staged into LDS once per block by cooperative
//   agent u64 loads (8/thread) -> MFMA A-frags via ds_read_b128 (was: every
//   wave re-loading the slab with atomic loads -> 2.5x the LLC atomic ops).
//  Decoder (rewritten): ZERO inter-block sync. Rows are independent given
//   weights (feedback is per-row). 256 blocks x 16 rows, each block owns all
//   256 hid: h0/h1/c/pred all block-local (LDS/registers). Weights pre-packed
//   to bf16 MFMA-fragment order by pack_kernel, streamed from L2 each step via
//   plain coalesced 16B loads (768KB/block/step, L2-resident). No flags.

typedef short short8v __attribute__((ext_vector_type(8)));
typedef float float4v __attribute__((ext_vector_type(4)));
typedef unsigned long long u64;
#define MFMA(a,b,c) __builtin_amdgcn_mfma_f32_16x16x32_bf16((a),(b),(c),0,0,0)

#define HIDN 256
#define TLEN 512
#define HPE  ((size_t)256 * HIDN)    // enc h slot elements (128 KB)

__device__ __forceinline__ unsigned short f2b(float f) {
    unsigned int u = __float_as_uint(f);
    unsigned int r = ((u >> 16) & 1u) + 0x7FFFu;
    return (unsigned short)((u + r) >> 16);
}
__device__ __forceinline__ float sigf(float x) { return 1.0f / (1.0f + __expf(-x)); }
__device__ __forceinline__ float tanhf2(float x) { return 1.0f - 2.0f / (1.0f + __expf(2.0f * x)); }

// pack 2 adjacent-hid bf16 via lane^1 shuffle; even lane does agent u32 store.
__device__ __forceinline__ void hpair_store(unsigned short* buf, int row, int hid,
                                            float h, int lane) {
    unsigned int mine = f2b(h);
    unsigned int part = (unsigned int)__shfl_xor((int)mine, 1);
    if (!(lane & 1)) {
        __hip_atomic_store((unsigned int*)&buf[(size_t)row * HIDN + hid],
                           mine | (part << 16),
                           __ATOMIC_RELAXED, __HIP_MEMORY_SCOPE_AGENT);
    }
}

// group barrier over 16 blocks; slots fl[0..15]; monotonic targets. [R7-proven]
__device__ __forceinline__ void bar_sync(unsigned int* fl, int slot, unsigned int target,
                                         int lane, int tid, int& dead) {
    __syncthreads();   // vmcnt drain: this block's agent h stores complete at LLC
    if (tid == 0)
        __hip_atomic_store(&fl[slot], target, __ATOMIC_RELAXED, __HIP_MEMORY_SCOPE_AGENT);
    if (!dead) {
        int guard = 0;
        for (;;) {
            unsigned int v = 0xFFFFFFFFu;
            if (lane < 16)
                v = __hip_atomic_load(&fl[lane], __ATOMIC_RELAXED, __HIP_MEMORY_SCOPE_AGENT);
            if (__ballot(v >= target) == ~0ull) break;
            if (++guard > (1 << 20)) { dead = 1; break; }
        }
    }
    __builtin_amdgcn_fence(__ATOMIC_ACQUIRE, "workgroup");  // compiler ordering only
}

// ==================== DEC WEIGHT PACK (one-time) ====================
// pk slot = ((mat*64 + n)*8 + kc)*64 + lane; 8 bf16 per slot (16B).
// Element: W[n*16 + (lane&15)][kc*32 + (lane>>4)*8 + i]  (B-frag layout).
__global__ __launch_bounds__(256) void pack_kernel(
    const float* __restrict__ Whh0, const float* __restrict__ Wih1,
    const float* __restrict__ Whh1, unsigned short* __restrict__ pk)
{
    int gid = blockIdx.x * 256 + threadIdx.x;   // 0..98303
    int lane = gid & 63;
    int kc = (gid >> 6) & 7;
    int n  = (gid >> 9) & 63;
    int mat = gid >> 15;
    const float* W = (mat == 0) ? Whh0 : ((mat == 1) ? Wih1 : Whh1);
    const float* p = W + (size_t)(n * 16 + (lane & 15)) * HIDN
                       + (kc << 5) + ((lane >> 4) << 3);
    short8v v;
#pragma unroll
    for (int i = 0; i < 8; ++i) v[i] = (short)f2b(p[i]);
    *(short8v*)&pk[(size_t)gid << 3] = v;
}

// ============================ ENCODER ============================
__global__ __launch_bounds__(256, 1) void enc_kernel(
    const float* __restrict__ x,
    const float* __restrict__ Wih0, const float* __restrict__ Whh0, const float* __restrict__ b0,
    const float* __restrict__ Wih1, const float* __restrict__ Whh1, const float* __restrict__ b1,
    unsigned short* __restrict__ h0e, unsigned short* __restrict__ h1e,   // [2][256][256]
    unsigned short* __restrict__ finh0, unsigned short* __restrict__ finh1,
    float* __restrict__ finc0, float* __restrict__ finc1,
    unsigned int* __restrict__ flags)
{
    const int tid = threadIdx.x, lane = tid & 63, wv = tid >> 6;
    const int bt = blockIdx.x & 15, hs = blockIdx.x >> 4;
    const int row0 = bt << 4, hidb = hs << 4;
    const int l15 = lane & 15, q = lane >> 4, q8 = q << 3;

    __shared__ float gt[12][16][17];
    __shared__ float xt[16][TLEN + 1];
    __shared__ unsigned short hst0[16][264], hst1[16][264];   // +8 pad: 2-way banks

    for (int idx = tid; idx < 16 * TLEN; idx += 256) {
        int r = idx >> 9, c = idx & 511;
        xt[r][c] = x[(size_t)(row0 + r) * TLEN + c];
    }

    // register weights: wave wv owns pairs p = wv*3+j, p=(mat*4+gate)
    short8v wf[3][8];
    {
        const float* Ws[3] = {Whh0, Wih1, Whh1};
#pragma unroll
        for (int j = 0; j < 3; ++j) {
            int p = wv * 3 + j;
            int mat = p >> 2, g = p & 3;
            const float* rp = Ws[mat] + (size_t)((g << 8) + hidb + l15) * HIDN + q8;
#pragma unroll
            for (int kc = 0; kc < 8; ++kc) {
                short8v v;
#pragma unroll
                for (int i = 0; i < 8; ++i) v[i] = (short)f2b(rp[(kc << 5) + i]);
                wf[j][kc] = v;
            }
        }
    }

    const int erow = tid >> 4, ehid = tid & 15;
    const int grow = row0 + erow, ghid = hidb + ehid;
    float wx[4], bb0v[4], bb1v[4];
#pragma unroll
    for (int g = 0; g < 4; ++g) {
        wx[g]   = Wih0[(g << 8) + ghid];
        bb0v[g] = b0[(g << 8) + ghid];
        bb1v[g] = b1[(g << 8) + ghid];
    }
    float c0 = 0.f, c1 = 0.f;
    unsigned int* fl = flags + (bt << 4);
    int dead = 0;
    const bool useH0 = (wv <= 2), useH1 = (wv >= 2);
    __syncthreads();   // xt ready

    for (int s = 1; s <= 513; ++s) {
        const unsigned short* hr0 = h0e + (size_t)((s - 1) & 1) * HPE;
        const unsigned short* hr1 = h1e + (size_t)((s - 1) & 1) * HPE;
        unsigned short* hw0 = h0e + (size_t)(s & 1) * HPE;
        unsigned short* hw1 = h1e + (size_t)(s & 1) * HPE;

        // cooperative stage of peer h slabs (agent u64 loads, 8/thread total)
        if (s >= 2) {
#pragma unroll
            for (int k = 0; k < 4; ++k) {
                int oo = tid + (k << 8);        // 0..1023 u64 slots
                int r = oo >> 6, cu = oo & 63;  // row, u64-in-row
                u64 v = __hip_atomic_load((const u64*)&hr0[(size_t)(row0 + r) * HIDN + (cu << 2)],
                                          __ATOMIC_RELAXED, __HIP_MEMORY_SCOPE_AGENT);
                *(u64*)&hst0[r][cu << 2] = v;
            }
        }
        if (s >= 3) {
#pragma unroll
            for (int k = 0; k < 4; ++k) {
                int oo = tid + (k << 8);
                int r = oo >> 6, cu = oo & 63;
                u64 v = __hip_atomic_load((const u64*)&hr1[(size_t)(row0 + r) * HIDN + (cu << 2)],
                                          __ATOMIC_RELAXED, __HIP_MEMORY_SCOPE_AGENT);
                *(u64*)&hst1[r][cu << 2] = v;
            }
        }
        __syncthreads();

        float4v acc[3] = {{0,0,0,0},{0,0,0,0},{0,0,0,0}};
        short8v a0f[8], a1f[8];
        if (useH0 && s >= 2) {
#pragma unroll
            for (int kc = 0; kc < 8; ++kc) a0f[kc] = *(const short8v*)&hst0[l15][(kc << 5) + q8];
        }
        if (useH1 && s >= 3) {
#pragma unroll
            for (int kc = 0; kc < 8; ++kc) a1f[kc] = *(const short8v*)&hst1[l15][(kc << 5) + q8];
        }
#pragma unroll
        for (int j = 0; j < 3; ++j) {
            int p = wv * 3 + j;
            int mat = p >> 2;
            bool active = (mat == 0) ? (s >= 2 && s <= 512)
                        : (mat == 1) ? (s >= 2)
                                     : (s >= 3);
            if (active) {
                if (mat == 2) {
#pragma unroll
                    for (int kc = 0; kc < 8; ++kc) acc[j] = MFMA(a1f[kc], wf[j][kc], acc[j]);
                } else {
#pragma unroll
                    for (int kc = 0; kc < 8; ++kc) acc[j] = MFMA(a0f[kc], wf[j][kc], acc[j]);
                }
            }
        }
#pragma unroll
        for (int j = 0; j < 3; ++j) {
            int p = wv * 3 + j;
#pragma unroll
            for (int r = 0; r < 4; ++r) gt[p][(q << 2) + r][l15] = acc[j][r];
        }
        __syncthreads();

        if (s <= 512) {
            float xv = xt[erow][s - 1];
            float gi = gt[0][erow][ehid] + wx[0] * xv + bb0v[0];
            float gf = gt[1][erow][ehid] + wx[1] * xv + bb0v[1];
            float gg = gt[2][erow][ehid] + wx[2] * xv + bb0v[2];
            float go = gt[3][erow][ehid] + wx[3] * xv + bb0v[3];
            c0 = sigf(gf) * c0 + sigf(gi) * tanhf2(gg);
            float h0n = sigf(go) * tanhf2(c0);
            hpair_store(hw0, grow, ghid, h0n, lane);
            if (s == 512) {
                finh0[(size_t)grow * HIDN + ghid] = f2b(h0n);
                finc0[(size_t)grow * HIDN + ghid] = c0;
            }
        }
        if (s >= 2) {
            float gi = gt[4][erow][ehid] + gt[8][erow][ehid]  + bb1v[0];
            float gf = gt[5][erow][ehid] + gt[9][erow][ehid]  + bb1v[1];
            float gg = gt[6][erow][ehid] + gt[10][erow][ehid] + bb1v[2];
            float go = gt[7][erow][ehid] + gt[11][erow][ehid] + bb1v[3];
            c1 = sigf(gf) * c1 + sigf(gi) * tanhf2(gg);
            float h1n = sigf(go) * tanhf2(c1);
            hpair_store(hw1, grow, ghid, h1n, lane);
            if (s == 513) {
                finh1[(size_t)grow * HIDN + ghid] = f2b(h1n);
                finc1[(size_t)grow * HIDN + ghid] = c1;
            }
        }
        bar_sync(fl, hs, (unsigned int)s, lane, tid, dead);
    }
}

// ============================ DECODER (no inter-block sync) ============================
// block = 16 rows (rg = blk*16+i), all 256 hid. Wave wv owns hid [wv*64, wv*64+64).
// gates N-frag n = type*16 + wv*4 + j  (gate-col = n*16 + (lane&15)).
__global__ __launch_bounds__(256, 1) void dec_kernel(
    const unsigned short* __restrict__ pk,
    const float* __restrict__ Wih0, const float* __restrict__ b0,
    const float* __restrict__ b1,
    const float* __restrict__ outW, const float* __restrict__ outb,
    const float* __restrict__ dinit,
    const unsigned short* __restrict__ finh0, const unsigned short* __restrict__ finh1,
    const float* __restrict__ finc0, const float* __restrict__ finc1,
    float* __restrict__ out)
{
    const int tid = threadIdx.x, lane = tid & 63, wv = tid >> 6;
    const int blk = blockIdx.x;
    const int l15 = lane & 15, q = lane >> 4, q8 = q << 3;
    const int rbase = blk << 4;

    __shared__ unsigned short hst0[16][264], hst1[16][264];
    __shared__ float predp[4][16];
    __shared__ float pr[16];

    float wx[4][4], bv0[4][4], bv1[4][4], ow[4];
#pragma unroll
    for (int j = 0; j < 4; ++j) {
        int hid = (wv << 6) + (j << 4) + l15;
        ow[j] = outW[hid];
#pragma unroll
        for (int ty = 0; ty < 4; ++ty) {
            wx[ty][j]  = Wih0[(ty << 8) + hid];
            bv0[ty][j] = b0[(ty << 8) + hid];
            bv1[ty][j] = b1[(ty << 8) + hid];
        }
    }
    const float outb_v = outb[0];

    // init state from encoder outputs (cross-kernel: plain loads OK)
    short8v h0A[8], h1A[8];
    {
        int frow = (rbase + l15) & 255;
#pragma unroll
        for (int kc = 0; kc < 8; ++kc) {
            h0A[kc] = *(const short8v*)&finh0[(size_t)frow * HIDN + (kc << 5) + q8];
            h1A[kc] = *(const short8v*)&finh1[(size_t)frow * HIDN + (kc << 5) + q8];
        }
    }
    float c0r[16], c1r[16];
#pragma unroll
    for (int j = 0; j < 4; ++j)
#pragma unroll
        for (int r = 0; r < 4; ++r) {
            int hid = (wv << 6) + (j << 4) + l15;
            int btr = (rbase + (q << 2) + r) & 255;
            c0r[(j << 2) + r] = finc0[(size_t)btr * HIDN + hid];
            c1r[(j << 2) + r] = finc1[(size_t)btr * HIDN + hid];
        }
    if (tid < 16) pr[tid] = dinit[rbase + tid];
    __syncthreads();

    const int nb = wv << 2;

    for (int t = 0; t < 64; ++t) {
        // ---- gates0 = h0 @ Whh0^T (mat 0) ----
        float4v acc[4][4];
#pragma unroll
        for (int ty = 0; ty < 4; ++ty)
#pragma unroll
            for (int j = 0; j < 4; ++j) acc[ty][j] = (float4v){0, 0, 0, 0};
#pragma unroll
        for (int kc = 0; kc < 8; ++kc) {
#pragma unroll
            for (int ty = 0; ty < 4; ++ty)
#pragma unroll
                for (int j = 0; j < 4; ++j) {
                    int n = (ty << 4) + nb + j;
                    short8v bf = *(const short8v*)&pk[(size_t)(((n << 3) + kc) << 9) + (lane << 3)];
                    acc[ty][j] = MFMA(h0A[kc], bf, acc[ty][j]);
                }
        }
        // ---- epilogue0: cells; h0 -> LDS ----
#pragma unroll
        for (int j = 0; j < 4; ++j)
#pragma unroll
            for (int r = 0; r < 4; ++r) {
                int row = (q << 2) + r;
                float inp = pr[row];
                float gi = acc[0][j][r] + wx[0][j] * inp + bv0[0][j];
                float gf = acc[1][j][r] + wx[1][j] * inp + bv0[1][j];
                float gg = acc[2][j][r] + wx[2][j] * inp + bv0[2][j];
                float go = acc[3][j][r] + wx[3][j] * inp + bv0[3][j];
                int ci = (j << 2) + r;
                c0r[ci] = sigf(gf) * c0r[ci] + sigf(gi) * tanhf2(gg);
                float h0n = sigf(go) * tanhf2(c0r[ci]);
                unsigned int mine = f2b(h0n);
                unsigned int part = (unsigned int)__shfl_xor((int)mine, 1);
                if (!(l15 & 1))
                    *(unsigned int*)&hst0[row][(wv << 6) + (j << 4) + l15] = mine | (part << 16);
            }
        __syncthreads();
#pragma unroll
        for (int kc = 0; kc < 8; ++kc)
            h0A[kc] = *(const short8v*)&hst0[l15][(kc << 5) + q8];

        // ---- gates1 = h0 @ Wih1^T (mat 1) + h1 @ Whh1^T (mat 2) ----
        float4v ac1[4][4];
#pragma unroll
        for (int ty = 0; ty < 4; ++ty)
#pragma unroll
            for (int j = 0; j < 4; ++j) ac1[ty][j] = (float4v){0, 0, 0, 0};
#pragma unroll
        for (int kc = 0; kc < 8; ++kc) {
#pragma unroll
            for (int ty = 0; ty < 4; ++ty)
#pragma unroll
                for (int j = 0; j < 4; ++j) {
                    int n = (ty << 4) + nb + j;
                    short8v bf = *(const short8v*)&pk[(size_t)((((64 + n) << 3) + kc) << 9) + (lane << 3)];
                    ac1[ty][j] = MFMA(h0A[kc], bf, ac1[ty][j]);
                }
        }
#pragma unroll
        for (int kc = 0; kc < 8; ++kc) {
#pragma unroll
            for (int ty = 0; ty < 4; ++ty)
#pragma unroll
                for (int j = 0; j < 4; ++j) {
                    int n = (ty << 4) + nb + j;
                    short8v bf = *(const short8v*)&pk[(size_t)((((128 + n) << 3) + kc) << 9) + (lane << 3)];
                    ac1[ty][j] = MFMA(h1A[kc], bf, ac1[ty][j]);
                }
        }
        // ---- epilogue1: cells; h1 -> LDS; pred partials ----
        float pp[4] = {0.f, 0.f, 0.f, 0.f};
#pragma unroll
        for (int j = 0; j < 4; ++j)
#pragma unroll
            for (int r = 0; r < 4; ++r) {
                int row = (q << 2) + r;
                float gi = ac1[0][j][r] + bv1[0][j];
                float gf = ac1[1][j][r] + bv1[1][j];
                float gg = ac1[2][j][r] + bv1[2][j];
                float go = ac1[3][j][r] + bv1[3][j];
                int ci = (j << 2) + r;
                c1r[ci] = sigf(gf) * c1r[ci] + sigf(gi) * tanhf2(gg);
                float h1n = sigf(go) * tanhf2(c1r[ci]);
                pp[r] += h1n * ow[j];
                unsigned int mine = f2b(h1n);
                unsigned int part = (unsigned int)__shfl_xor((int)mine, 1);
                if (!(l15 & 1))
                    *(unsigned int*)&hst1[row][(wv << 6) + (j << 4) + l15] = mine | (part << 16);
            }
#pragma unroll
        for (int off = 1; off < 16; off <<= 1)
#pragma unroll
            for (int r = 0; r < 4; ++r) pp[r] += __shfl_xor(pp[r], off);
        if (l15 == 0) {
#pragma unroll
            for (int r = 0; r < 4; ++r) predp[wv][(q << 2) + r] = pp[r];
        }
        __syncthreads();
#pragma unroll
        for (int kc = 0; kc < 8; ++kc)
            h1A[kc] = *(const short8v*)&hst1[l15][(kc << 5) + q8];
        if (tid < 16) {
            float s = predp[0][tid] + predp[1][tid] + predp[2][tid] + predp[3][tid] + outb_v;
            pr[tid] = s;
            int rg = rbase + tid;
            out[(size_t)(((rg & 255) << 4) + (rg >> 8)) * 64 + t] = s;
        }
        __syncthreads();
    }
}

extern "C" void kernel_launch(void* const* d_in, const int* in_sizes, int n_in,
                              void* d_out, int out_size, void* d_ws, size_t ws_size,
                              hipStream_t stream) {
    (void)in_sizes; (void)n_in; (void)out_size; (void)ws_size;
    const float* x     = (const float*)d_in[0];
    const float* eWih0 = (const float*)d_in[1];
    const float* eWhh0 = (const float*)d_in[2];
    const float* eb0   = (const float*)d_in[3];
    const float* eWih1 = (const float*)d_in[4];
    const float* eWhh1 = (const float*)d_in[5];
    const float* eb1   = (const float*)d_in[6];
    const float* dWih0 = (const float*)d_in[7];
    const float* dWhh0 = (const float*)d_in[8];
    const float* db0   = (const float*)d_in[9];
    const float* dWih1 = (const float*)d_in[10];
    const float* dWhh1 = (const float*)d_in[11];
    const float* db1   = (const float*)d_in[12];
    const float* outW  = (const float*)d_in[13];
    const float* outb  = (const float*)d_in[14];
    const float* dinit = (const float*)d_in[15];

    char* ws = (char*)d_ws;
    unsigned short* h0e   = (unsigned short*)(ws);              // 256 KB
    unsigned short* h1e   = (unsigned short*)(ws + 262144);     // 256 KB
    unsigned short* finh0 = (unsigned short*)(ws + 524288);     // 128 KB
    unsigned short* finh1 = (unsigned short*)(ws + 655360);     // 128 KB
    float* finc0          = (float*)(ws + 786432);              // 256 KB
    float* finc1          = (float*)(ws + 1048576);             // 256 KB
    unsigned int* fle     = (unsigned int*)(ws + 1310720);      // 1 KB
    unsigned short* pk    = (unsigned short*)(ws + 1311744);    // 1.5 MB packed dec weights

    hipMemsetAsync(ws + 1310720, 0, 1024, stream);
    pack_kernel<<<384, 256, 0, stream>>>(dWhh0, dWih1, dWhh1, pk);
    enc_kernel<<<256, 256, 0, stream>>>(x, eWih0, eWhh0, eb0, eWih1, eWhh1, eb1,
                                        h0e, h1e, finh0, finh1, finc0, finc1, fle);
    dec_kernel<<<256, 256, 0, stream>>>(pk, dWih0, db0, db1, outW, outb, dinit,
                                        finh0, finh1, finc0, finc1, (float*)d_out);
}

// Round 9
// 4565.615 us; speedup vs baseline: 2.8206x; 2.8206x over previous
//
#include <hip/hip_runtime.h>
#include <stdint.h>

// Seq2seq LSTM, f32 in/out, bf16 MFMA, fp32 cell state.
// R9:
//  Encoder: unchanged from R8 (persistent, 16x16 groups, register weights,
//   agent-atomic h exchange + flag barrier, LDS staging). ~2.4ms, latency-bound.
//  Decoder: MULTI-KERNEL, 2 launches per step (A=layer0, B=layer1+pred), 64 steps.
//   Kernel boundaries give full coherence -> plain loads/stores only. The 8x
//   h-slab broadcast is served by per-XCD L2 (plain, cacheable). Weights packed
//   to bf16 MFMA B-frag layout once (pack_kernel), staged to LDS per launch.
//   pred reduced with f32 atomicAdd into per-step slots (read next launch).
//   Partition: 256 blocks = 32 row-groups(128 rows) x 8 hid-slices(32 hid).

typedef short short8v __attribute__((ext_vector_type(8)));
typedef float float4v __attribute__((ext_vector_type(4)));
typedef unsigned long long u64;
#define MFMA(a,b,c) __builtin_amdgcn_mfma_f32_16x16x32_bf16((a),(b),(c),0,0,0)

#define HIDN 256
#define TLEN 512
#define HPE  ((size_t)256 * HIDN)     // enc h slot elements (128 KB)
#define HPD  ((size_t)4096 * HIDN)    // dec h slot elements (2 MB bf16)

__device__ __forceinline__ unsigned short f2b(float f) {
    unsigned int u = __float_as_uint(f);
    unsigned int r = ((u >> 16) & 1u) + 0x7FFFu;
    return (unsigned short)((u + r) >> 16);
}
__device__ __forceinline__ float sigf(float x) { return 1.0f / (1.0f + __expf(-x)); }
__device__ __forceinline__ float tanhf2(float x) { return 1.0f - 2.0f / (1.0f + __expf(2.0f * x)); }

__device__ __forceinline__ void hpair_store(unsigned short* buf, int row, int hid,
                                            float h, int lane) {
    unsigned int mine = f2b(h);
    unsigned int part = (unsigned int)__shfl_xor((int)mine, 1);
    if (!(lane & 1)) {
        __hip_atomic_store((unsigned int*)&buf[(size_t)row * HIDN + hid],
                           mine | (part << 16),
                           __ATOMIC_RELAXED, __HIP_MEMORY_SCOPE_AGENT);
    }
}

__device__ __forceinline__ void bar_sync(unsigned int* fl, int slot, unsigned int target,
                                         int lane, int tid, int& dead) {
    __syncthreads();
    if (tid == 0)
        __hip_atomic_store(&fl[slot], target, __ATOMIC_RELAXED, __HIP_MEMORY_SCOPE_AGENT);
    if (!dead) {
        int guard = 0;
        for (;;) {
            unsigned int v = 0xFFFFFFFFu;
            if (lane < 16)
                v = __hip_atomic_load(&fl[lane], __ATOMIC_RELAXED, __HIP_MEMORY_SCOPE_AGENT);
            if (__ballot(v >= target) == ~0ull) break;
            if (++guard > (1 << 20)) { dead = 1; break; }
        }
    }
    __builtin_amdgcn_fence(__ATOMIC_ACQUIRE, "workgroup");
}

// ==================== DEC WEIGHT PACK (one-time) ====================
// pk slot = ((mat*64 + n)*8 + kc)*64 + lane; element W[n*16+(lane&15)][kc*32+(lane>>4)*8+i]
__global__ __launch_bounds__(256) void pack_kernel(
    const float* __restrict__ Whh0, const float* __restrict__ Wih1,
    const float* __restrict__ Whh1, unsigned short* __restrict__ pk)
{
    int gid = blockIdx.x * 256 + threadIdx.x;   // 0..98303
    int lane = gid & 63;
    int kc = (gid >> 6) & 7;
    int n  = (gid >> 9) & 63;
    int mat = gid >> 15;
    const float* W = (mat == 0) ? Whh0 : ((mat == 1) ? Wih1 : Whh1);
    const float* p = W + (size_t)(n * 16 + (lane & 15)) * HIDN
                       + (kc << 5) + ((lane >> 4) << 3);
    short8v v;
#pragma unroll
    for (int i = 0; i < 8; ++i) v[i] = (short)f2b(p[i]);
    *(short8v*)&pk[(size_t)gid << 3] = v;
}

// ============================ ENCODER (R8, unchanged) ============================
__global__ __launch_bounds__(256, 1) void enc_kernel(
    const float* __restrict__ x,
    const float* __restrict__ Wih0, const float* __restrict__ Whh0, const float* __restrict__ b0,
    const float* __restrict__ Wih1, const float* __restrict__ Whh1, const float* __restrict__ b1,
    unsigned short* __restrict__ h0e, unsigned short* __restrict__ h1e,
    unsigned short* __restrict__ finh0, unsigned short* __restrict__ finh1,
    float* __restrict__ finc0, float* __restrict__ finc1,
    unsigned int* __restrict__ flags)
{
    const int tid = threadIdx.x, lane = tid & 63, wv = tid >> 6;
    const int bt = blockIdx.x & 15, hs = blockIdx.x >> 4;
    const int row0 = bt << 4, hidb = hs << 4;
    const int l15 = lane & 15, q = lane >> 4, q8 = q << 3;

    __shared__ float gt[12][16][17];
    __shared__ float xt[16][TLEN + 1];
    __shared__ unsigned short hst0[16][264], hst1[16][264];

    for (int idx = tid; idx < 16 * TLEN; idx += 256) {
        int r = idx >> 9, c = idx & 511;
        xt[r][c] = x[(size_t)(row0 + r) * TLEN + c];
    }

    short8v wf[3][8];
    {
        const float* Ws[3] = {Whh0, Wih1, Whh1};
#pragma unroll
        for (int j = 0; j < 3; ++j) {
            int p = wv * 3 + j;
            int mat = p >> 2, g = p & 3;
            const float* rp = Ws[mat] + (size_t)((g << 8) + hidb + l15) * HIDN + q8;
#pragma unroll
            for (int kc = 0; kc < 8; ++kc) {
                short8v v;
#pragma unroll
                for (int i = 0; i < 8; ++i) v[i] = (short)f2b(rp[(kc << 5) + i]);
                wf[j][kc] = v;
            }
        }
    }

    const int erow = tid >> 4, ehid = tid & 15;
    const int grow = row0 + erow, ghid = hidb + ehid;
    float wx[4], bb0v[4], bb1v[4];
#pragma unroll
    for (int g = 0; g < 4; ++g) {
        wx[g]   = Wih0[(g << 8) + ghid];
        bb0v[g] = b0[(g << 8) + ghid];
        bb1v[g] = b1[(g << 8) + ghid];
    }
    float c0 = 0.f, c1 = 0.f;
    unsigned int* fl = flags + (bt << 4);
    int dead = 0;
    const bool useH0 = (wv <= 2), useH1 = (wv >= 2);
    __syncthreads();

    for (int s = 1; s <= 513; ++s) {
        const unsigned short* hr0 = h0e + (size_t)((s - 1) & 1) * HPE;
        const unsigned short* hr1 = h1e + (size_t)((s - 1) & 1) * HPE;
        unsigned short* hw0 = h0e + (size_t)(s & 1) * HPE;
        unsigned short* hw1 = h1e + (size_t)(s & 1) * HPE;

        if (s >= 2) {
#pragma unroll
            for (int k = 0; k < 4; ++k) {
                int oo = tid + (k << 8);
                int r = oo >> 6, cu = oo & 63;
                u64 v = __hip_atomic_load((const u64*)&hr0[(size_t)(row0 + r) * HIDN + (cu << 2)],
                                          __ATOMIC_RELAXED, __HIP_MEMORY_SCOPE_AGENT);
                *(u64*)&hst0[r][cu << 2] = v;
            }
        }
        if (s >= 3) {
#pragma unroll
            for (int k = 0; k < 4; ++k) {
                int oo = tid + (k << 8);
                int r = oo >> 6, cu = oo & 63;
                u64 v = __hip_atomic_load((const u64*)&hr1[(size_t)(row0 + r) * HIDN + (cu << 2)],
                                          __ATOMIC_RELAXED, __HIP_MEMORY_SCOPE_AGENT);
                *(u64*)&hst1[r][cu << 2] = v;
            }
        }
        __syncthreads();

        float4v acc[3] = {{0,0,0,0},{0,0,0,0},{0,0,0,0}};
        short8v a0f[8], a1f[8];
        if (useH0 && s >= 2) {
#pragma unroll
            for (int kc = 0; kc < 8; ++kc) a0f[kc] = *(const short8v*)&hst0[l15][(kc << 5) + q8];
        }
        if (useH1 && s >= 3) {
#pragma unroll
            for (int kc = 0; kc < 8; ++kc) a1f[kc] = *(const short8v*)&hst1[l15][(kc << 5) + q8];
        }
#pragma unroll
        for (int j = 0; j < 3; ++j) {
            int p = wv * 3 + j;
            int mat = p >> 2;
            bool active = (mat == 0) ? (s >= 2 && s <= 512)
                        : (mat == 1) ? (s >= 2)
                                     : (s >= 3);
            if (active) {
                if (mat == 2) {
#pragma unroll
                    for (int kc = 0; kc < 8; ++kc) acc[j] = MFMA(a1f[kc], wf[j][kc], acc[j]);
                } else {
#pragma unroll
                    for (int kc = 0; kc < 8; ++kc) acc[j] = MFMA(a0f[kc], wf[j][kc], acc[j]);
                }
            }
        }
#pragma unroll
        for (int j = 0; j < 3; ++j) {
            int p = wv * 3 + j;
#pragma unroll
            for (int r = 0; r < 4; ++r) gt[p][(q << 2) + r][l15] = acc[j][r];
        }
        __syncthreads();

        if (s <= 512) {
            float xv = xt[erow][s - 1];
            float gi = gt[0][erow][ehid] + wx[0] * xv + bb0v[0];
            float gf = gt[1][erow][ehid] + wx[1] * xv + bb0v[1];
            float gg = gt[2][erow][ehid] + wx[2] * xv + bb0v[2];
            float go = gt[3][erow][ehid] + wx[3] * xv + bb0v[3];
            c0 = sigf(gf) * c0 + sigf(gi) * tanhf2(gg);
            float h0n = sigf(go) * tanhf2(c0);
            hpair_store(hw0, grow, ghid, h0n, lane);
            if (s == 512) {
                finh0[(size_t)grow * HIDN + ghid] = f2b(h0n);
                finc0[(size_t)grow * HIDN + ghid] = c0;
            }
        }
        if (s >= 2) {
            float gi = gt[4][erow][ehid] + gt[8][erow][ehid]  + bb1v[0];
            float gf = gt[5][erow][ehid] + gt[9][erow][ehid]  + bb1v[1];
            float gg = gt[6][erow][ehid] + gt[10][erow][ehid] + bb1v[2];
            float go = gt[7][erow][ehid] + gt[11][erow][ehid] + bb1v[3];
            c1 = sigf(gf) * c1 + sigf(gi) * tanhf2(gg);
            float h1n = sigf(go) * tanhf2(c1);
            hpair_store(hw1, grow, ghid, h1n, lane);
            if (s == 513) {
                finh1[(size_t)grow * HIDN + ghid] = f2b(h1n);
                finc1[(size_t)grow * HIDN + ghid] = c1;
            }
        }
        bar_sync(fl, hs, (unsigned int)s, lane, tid, dead);
    }
}

// ===================== DECODER phase A: layer0 at step t =====================
// 256 blocks = 32 row-groups(128 rows) x 8 hid-slices(32 hid). Plain mem only.
__global__ __launch_bounds__(256, 1) void decA_kernel(
    const unsigned short* __restrict__ pk,
    const float* __restrict__ Wih0, const float* __restrict__ b0,
    const float* __restrict__ outb, const float* __restrict__ dinit,
    const unsigned short* __restrict__ finh0, const float* __restrict__ finc0,
    const unsigned short* __restrict__ h0in, unsigned short* __restrict__ h0out,
    float* __restrict__ c0buf, const float* __restrict__ predprev,
    float* __restrict__ out, int t)
{
    extern __shared__ unsigned short wlds[];   // 64KB: slot (nf*8+kc)*64+ln
    const int tid = threadIdx.x, lane = tid & 63, wv = tid >> 6;
    const int rg = blockIdx.x >> 3, hsl = blockIdx.x & 7;
    const int row0 = rg << 7, hidb = hsl << 5;
    const int l15 = lane & 15, q = lane >> 4, q8 = q << 3;

    // stage Whh0 B-frags (global n = gate*16 + hsl*2 + u; nf = gate*2+u)
#pragma unroll
    for (int k = 0; k < 16; ++k) {
        int sl = tid + (k << 8);
        int ln = sl & 63, kc = (sl >> 6) & 7, nf = sl >> 9;
        int n = ((nf >> 1) << 4) + (hsl << 1) + (nf & 1);
        *(short8v*)&wlds[sl << 3] =
            *(const short8v*)&pk[((size_t)((n << 3) + kc) << 9) + (ln << 3)];
    }
    // A-frags (plain)
    short8v af[2][8];
#pragma unroll
    for (int m = 0; m < 2; ++m) {
        int row = row0 + (wv << 5) + (m << 4) + l15;
        const unsigned short* p = (t == 0) ? finh0 + (size_t)(row & 255) * HIDN + q8
                                           : h0in + (size_t)row * HIDN + q8;
#pragma unroll
        for (int kc = 0; kc < 8; ++kc) af[m][kc] = *(const short8v*)&p[kc << 5];
    }
    __syncthreads();

    float4v acc[2][8];
#pragma unroll
    for (int m = 0; m < 2; ++m)
#pragma unroll
        for (int nf = 0; nf < 8; ++nf) acc[m][nf] = (float4v){0, 0, 0, 0};
#pragma unroll
    for (int kc = 0; kc < 8; ++kc)
#pragma unroll
        for (int nf = 0; nf < 8; ++nf) {
            short8v bf = *(const short8v*)&wlds[(size_t)(((((nf << 3) + kc) << 6) + lane) << 3)];
            acc[0][nf] = MFMA(af[0][kc], bf, acc[0][nf]);
            acc[1][nf] = MFMA(af[1][kc], bf, acc[1][nf]);
        }

    const float outb_v = outb[0];
    float wx2[2][4], bb2[2][4];
#pragma unroll
    for (int u = 0; u < 2; ++u) {
        int hid = hidb + (u << 4) + l15;
#pragma unroll
        for (int g = 0; g < 4; ++g) {
            wx2[u][g] = Wih0[(g << 8) + hid];
            bb2[u][g] = b0[(g << 8) + hid];
        }
    }
#pragma unroll
    for (int m = 0; m < 2; ++m)
#pragma unroll
        for (int u = 0; u < 2; ++u) {
            int hid = hidb + (u << 4) + l15;
#pragma unroll
            for (int r = 0; r < 4; ++r) {
                int row = row0 + (wv << 5) + (m << 4) + (q << 2) + r;
                float inp = (t == 0) ? dinit[row] : (predprev[row] + outb_v);
                float cold = (t == 0) ? finc0[(size_t)(row & 255) * HIDN + hid]
                                      : c0buf[(size_t)row * HIDN + hid];
                float gi = acc[m][0 + u][r] + wx2[u][0] * inp + bb2[u][0];
                float gf = acc[m][2 + u][r] + wx2[u][1] * inp + bb2[u][1];
                float gg = acc[m][4 + u][r] + wx2[u][2] * inp + bb2[u][2];
                float go = acc[m][6 + u][r] + wx2[u][3] * inp + bb2[u][3];
                float cn = sigf(gf) * cold + sigf(gi) * tanhf2(gg);
                c0buf[(size_t)row * HIDN + hid] = cn;
                float h0n = sigf(go) * tanhf2(cn);
                unsigned int mine = f2b(h0n);
                unsigned int part = (unsigned int)__shfl_xor((int)mine, 1);
                if (!(lane & 1))
                    *(unsigned int*)&h0out[(size_t)row * HIDN + hid] = mine | (part << 16);
            }
        }
    if (hsl == 0 && t > 0 && tid < 128) {
        int row = row0 + tid;
        out[(size_t)(((row & 255) << 4) + (row >> 8)) * 64 + (t - 1)] = predprev[row] + outb_v;
    }
}

// ===================== DECODER phase B: layer1+pred at step t =====================
__global__ __launch_bounds__(256, 1) void decB_kernel(
    const unsigned short* __restrict__ pk,
    const float* __restrict__ b1, const float* __restrict__ outW,
    const unsigned short* __restrict__ finh1, const float* __restrict__ finc1,
    const unsigned short* __restrict__ h0cur, const unsigned short* __restrict__ h1in,
    unsigned short* __restrict__ h1out, float* __restrict__ c1buf,
    float* __restrict__ predcur, int t)
{
    extern __shared__ unsigned short wlds[];   // 128KB: [mt][nf][kc][ln] 16B
    const int tid = threadIdx.x, lane = tid & 63, wv = tid >> 6;
    const int rg = blockIdx.x >> 3, hsl = blockIdx.x & 7;
    const int row0 = rg << 7, hidb = hsl << 5;
    const int l15 = lane & 15, q = lane >> 4, q8 = q << 3;

#pragma unroll
    for (int k = 0; k < 32; ++k) {
        int sl = tid + (k << 8);
        int ln = sl & 63, kc = (sl >> 6) & 7, nf = (sl >> 9) & 7, mt = sl >> 12;
        int n = ((mt + 1) << 6) + ((nf >> 1) << 4) + (hsl << 1) + (nf & 1);
        *(short8v*)&wlds[sl << 3] =
            *(const short8v*)&pk[((size_t)((n << 3) + kc) << 9) + (ln << 3)];
    }
    short8v a0[2][8], a1[2][8];
#pragma unroll
    for (int m = 0; m < 2; ++m) {
        int row = row0 + (wv << 5) + (m << 4) + l15;
        const unsigned short* p0 = h0cur + (size_t)row * HIDN + q8;
        const unsigned short* p1 = (t == 0) ? finh1 + (size_t)(row & 255) * HIDN + q8
                                            : h1in + (size_t)row * HIDN + q8;
#pragma unroll
        for (int kc = 0; kc < 8; ++kc) {
            a0[m][kc] = *(const short8v*)&p0[kc << 5];
            a1[m][kc] = *(const short8v*)&p1[kc << 5];
        }
    }
    __syncthreads();

    float4v acc[2][8];
#pragma unroll
    for (int m = 0; m < 2; ++m)
#pragma unroll
        for (int nf = 0; nf < 8; ++nf) acc[m][nf] = (float4v){0, 0, 0, 0};
#pragma unroll
    for (int kc = 0; kc < 8; ++kc)
#pragma unroll
        for (int nf = 0; nf < 8; ++nf) {
            short8v bf = *(const short8v*)&wlds[(size_t)(((((nf << 3) + kc) << 6) + lane) << 3)];
            acc[0][nf] = MFMA(a0[0][kc], bf, acc[0][nf]);
            acc[1][nf] = MFMA(a0[1][kc], bf, acc[1][nf]);
        }
#pragma unroll
    for (int kc = 0; kc < 8; ++kc)
#pragma unroll
        for (int nf = 0; nf < 8; ++nf) {
            short8v bf = *(const short8v*)&wlds[(size_t)((((32768 >> 3) + (((nf << 3) + kc) << 6) + lane) << 3))];
            acc[0][nf] = MFMA(a1[0][kc], bf, acc[0][nf]);
            acc[1][nf] = MFMA(a1[1][kc], bf, acc[1][nf]);
        }

    float ow2[2], bb2[2][4];
#pragma unroll
    for (int u = 0; u < 2; ++u) {
        int hid = hidb + (u << 4) + l15;
        ow2[u] = outW[hid];
#pragma unroll
        for (int g = 0; g < 4; ++g) bb2[u][g] = b1[(g << 8) + hid];
    }
    float pp[2][4] = {{0,0,0,0},{0,0,0,0}};
#pragma unroll
    for (int m = 0; m < 2; ++m)
#pragma unroll
        for (int u = 0; u < 2; ++u) {
            int hid = hidb + (u << 4) + l15;
#pragma unroll
            for (int r = 0; r < 4; ++r) {
                int row = row0 + (wv << 5) + (m << 4) + (q << 2) + r;
                float cold = (t == 0) ? finc1[(size_t)(row & 255) * HIDN + hid]
                                      : c1buf[(size_t)row * HIDN + hid];
                float gi = acc[m][0 + u][r] + bb2[u][0];
                float gf = acc[m][2 + u][r] + bb2[u][1];
                float gg = acc[m][4 + u][r] + bb2[u][2];
                float go = acc[m][6 + u][r] + bb2[u][3];
                float cn = sigf(gf) * cold + sigf(gi) * tanhf2(gg);
                c1buf[(size_t)row * HIDN + hid] = cn;
                float h1n = sigf(go) * tanhf2(cn);
                pp[m][r] += h1n * ow2[u];
                unsigned int mine = f2b(h1n);
                unsigned int part = (unsigned int)__shfl_xor((int)mine, 1);
                if (!(lane & 1))
                    *(unsigned int*)&h1out[(size_t)row * HIDN + hid] = mine | (part << 16);
            }
        }
#pragma unroll
    for (int off = 1; off < 16; off <<= 1)
#pragma unroll
        for (int m = 0; m < 2; ++m)
#pragma unroll
            for (int r = 0; r < 4; ++r) pp[m][r] += __shfl_xor(pp[m][r], off);
    if (l15 == 0) {
#pragma unroll
        for (int m = 0; m < 2; ++m)
#pragma unroll
            for (int r = 0; r < 4; ++r) {
                int row = row0 + (wv << 5) + (m << 4) + (q << 2) + r;
                atomicAdd(&predcur[row], pp[m][r]);
            }
    }
}

__global__ __launch_bounds__(256) void decC_kernel(const float* __restrict__ pred63,
                                                   const float* __restrict__ outb,
                                                   float* __restrict__ out) {
    int row = blockIdx.x * 256 + threadIdx.x;
    out[(size_t)(((row & 255) << 4) + (row >> 8)) * 64 + 63] = pred63[row] + outb[0];
}

extern "C" void kernel_launch(void* const* d_in, const int* in_sizes, int n_in,
                              void* d_out, int out_size, void* d_ws, size_t ws_size,
                              hipStream_t stream) {
    (void)in_sizes; (void)n_in; (void)out_size; (void)ws_size;
    const float* x     = (const float*)d_in[0];
    const float* eWih0 = (const float*)d_in[1];
    const float* eWhh0 = (const float*)d_in[2];
    const float* eb0   = (const float*)d_in[3];
    const float* eWih1 = (const float*)d_in[4];
    const float* eWhh1 = (const float*)d_in[5];
    const float* eb1   = (const float*)d_in[6];
    const float* dWih0 = (const float*)d_in[7];
    const float* dWhh0 = (const float*)d_in[8];
    const float* db0   = (const float*)d_in[9];
    const float* dWih1 = (const float*)d_in[10];
    const float* dWhh1 = (const float*)d_in[11];
    const float* db1   = (const float*)d_in[12];
    const float* outW  = (const float*)d_in[13];
    const float* outb  = (const float*)d_in[14];
    const float* dinit = (const float*)d_in[15];

    char* ws = (char*)d_ws;
    unsigned short* h0e   = (unsigned short*)(ws);               // 256 KB
    unsigned short* h1e   = (unsigned short*)(ws + 262144);      // 256 KB
    unsigned short* finh0 = (unsigned short*)(ws + 524288);      // 128 KB
    unsigned short* finh1 = (unsigned short*)(ws + 655360);      // 128 KB
    float* finc0          = (float*)(ws + 786432);               // 256 KB
    float* finc1          = (float*)(ws + 1048576);              // 256 KB
    unsigned int* fle     = (unsigned int*)(ws + 1310720);       // 1 KB
    unsigned short* pk    = (unsigned short*)(ws + 1311744);     // 1.5 MB
    unsigned short* h0d   = (unsigned short*)(ws + 2884608);     // 2x2 MB
    unsigned short* h1d   = (unsigned short*)(ws + 7078912);     // 2x2 MB
    float* c0buf          = (float*)(ws + 11273216);             // 4 MB
    float* c1buf          = (float*)(ws + 15467520);             // 4 MB
    float* predraw        = (float*)(ws + 19661824);             // 1 MB (64 x 4096)

    hipMemsetAsync(fle, 0, 1024, stream);
    hipMemsetAsync(predraw, 0, 64 * 4096 * 4, stream);
    hipFuncSetAttribute((const void*)decA_kernel,
                        hipFuncAttributeMaxDynamicSharedMemorySize, 65536);
    hipFuncSetAttribute((const void*)decB_kernel,
                        hipFuncAttributeMaxDynamicSharedMemorySize, 131072);

    pack_kernel<<<384, 256, 0, stream>>>(dWhh0, dWih1, dWhh1, pk);
    enc_kernel<<<256, 256, 0, stream>>>(x, eWih0, eWhh0, eb0, eWih1, eWhh1, eb1,
                                        h0e, h1e, finh0, finh1, finc0, finc1, fle);
    for (int t = 0; t < 64; ++t) {
        const unsigned short* h0in = h0d + (size_t)((t + 1) & 1) * HPD;
        unsigned short* h0o        = h0d + (size_t)(t & 1) * HPD;
        const unsigned short* h1in = h1d + (size_t)((t + 1) & 1) * HPD;
        unsigned short* h1o        = h1d + (size_t)(t & 1) * HPD;
        const float* pprev = predraw + (size_t)(t > 0 ? (t - 1) : 0) * 4096;
        decA_kernel<<<256, 256, 65536, stream>>>(pk, dWih0, db0, outb, dinit,
                                                 finh0, finc0, h0in, h0o, c0buf,
                                                 pprev, (float*)d_out, t);
        decB_kernel<<<256, 256, 131072, stream>>>(pk, db1, outW, finh1, finc1,
                                                  h0o, h1in, h1o, c1buf,
                                                  predraw + (size_t)t * 4096, t);
    }
    decC_kernel<<<16, 256, 0, stream>>>(predraw + (size_t)63 * 4096, outb, (float*)d_out);
}